// Round 1
// baseline (508.110 us; speedup 1.0000x reference)
//
#include <hip/hip_runtime.h>
#include <hip/hip_fp16.h>

#define NQ   40000
#define HN   32
#define CI   64
#define CO   64
#define KP   27
#define BQ   8

#define INV_EXT 11.547005383792515f   // 1 / (0.1/2*sqrt(3))
#define KP_S    0.057735026918962574f // 0.1/sqrt(3)

__global__ __launch_bounds__(256) void kpconv_kernel(
    const float* __restrict__ q_pts,
    const float* __restrict__ s_pts,
    const int*   __restrict__ inds,
    const float* __restrict__ x,
    const float* __restrict__ Wt,
    float*       __restrict__ out)
{
    __shared__ __align__(16) float  w_lds[BQ][HN][28];   // 28-pad for float4 reads
    __shared__ __align__(16) __half g_lds[BQ][KP][CI];
    __shared__ float nbr_lds[BQ][HN][3];
    __shared__ int   idx_lds[BQ][HN];
    __shared__ int   act[BQ][KP];

    const int tid  = threadIdx.x;
    const int base = blockIdx.x * BQ;
    const int lane = tid & 63;
    const int wid  = tid >> 6;

    // ---- Phase A: neighbor index + offset cache (1 elem / thread) ----
    {
        const int q = tid >> 5, h = tid & 31;
        const int n = base + q;
        if (n < NQ) {
            const int idx = inds[n * HN + h];
            idx_lds[q][h] = idx;
            nbr_lds[q][h][0] = s_pts[idx*3+0] - q_pts[n*3+0];
            nbr_lds[q][h][1] = s_pts[idx*3+1] - q_pts[n*3+1];
            nbr_lds[q][h][2] = s_pts[idx*3+2] - q_pts[n*3+2];
        } else {
            idx_lds[q][h] = 0;
            nbr_lds[q][h][0] = 1e9f;
            nbr_lds[q][h][1] = 1e9f;
            nbr_lds[q][h][2] = 1e9f;
        }
    }
    if (tid < BQ*KP) ((int*)act)[tid] = 0;
    __syncthreads();

    // ---- Phase B: influence weights, all lanes parallel over (q,h,l) ----
    for (int t = tid; t < BQ*HN*KP; t += 256) {
        const int q   = t / (HN*KP);
        const int rem = t - q*(HN*KP);
        const int h   = rem / KP;
        const int l   = rem - h*KP;
        const float kx = (float)(((l/3)%3) - 1) * KP_S;
        const float ky = (float)((l/9)     - 1) * KP_S;
        const float kz = (float)((l%3)     - 1) * KP_S;
        const float dx = nbr_lds[q][h][0] - kx;
        const float dy = nbr_lds[q][h][1] - ky;
        const float dz = nbr_lds[q][h][2] - kz;
        const float sq = dx*dx + dy*dy + dz*dz;
        const float w  = fmaxf(1.0f - sqrtf(sq) * INV_EXT, 0.0f);
        w_lds[q][h][l] = w;
        if (w > 0.0f) act[q][l] = 1;
    }
    __syncthreads();

    // ---- Phase C: g[l][i] accumulation; wave handles 2 queries, lane = i ----
    #pragma unroll
    for (int qq = 0; qq < 2; ++qq) {
        const int q = wid*2 + qq;
        float g[KP];
        #pragma unroll
        for (int l = 0; l < KP; ++l) g[l] = 0.0f;

        for (int h = 0; h < HN; ++h) {
            const int idx  = idx_lds[q][h];
            const float xv = x[idx*CI + lane];
            float wv[28];
            #pragma unroll
            for (int c = 0; c < 7; ++c) {
                const float4 t4 = ((const float4*)(&w_lds[q][h][0]))[c];
                wv[4*c+0] = t4.x; wv[4*c+1] = t4.y;
                wv[4*c+2] = t4.z; wv[4*c+3] = t4.w;
            }
            #pragma unroll
            for (int l = 0; l < KP; ++l) g[l] = fmaf(wv[l], xv, g[l]);
        }
        #pragma unroll
        for (int l = 0; l < KP; ++l) g_lds[q][l][lane] = __float2half(g[l]);
    }
    __syncthreads();

    // ---- Phase D: fx[o] = sum_l sum_i g[l][i] * W[l][i][o]; lane = o ----
    {
        const int qa = wid*2, qb = wid*2 + 1;
        float acc_a = 0.0f, acc_b = 0.0f;

        for (int l = 0; l < KP; ++l) {
            if ((act[qa][l] | act[qb][l]) == 0) continue;   // wave-uniform skip
            const float* Wl = Wt + (l*CI)*CO + lane;
            const __half2* ga = (const __half2*)(&g_lds[qa][l][0]);
            const __half2* gb = (const __half2*)(&g_lds[qb][l][0]);
            #pragma unroll
            for (int p = 0; p < CI/2; ++p) {
                const float2 fa = __half22float2(ga[p]);
                const float2 fb = __half22float2(gb[p]);
                const float w0 = Wl[(2*p+0)*CO];
                const float w1 = Wl[(2*p+1)*CO];
                acc_a = fmaf(fa.x, w0, acc_a);
                acc_b = fmaf(fb.x, w0, acc_b);
                acc_a = fmaf(fa.y, w1, acc_a);
                acc_b = fmaf(fb.y, w1, acc_b);
            }
        }
        const int na = base + qa, nb = base + qb;
        if (na < NQ) out[na*CO + lane] = acc_a;
        if (nb < NQ) out[nb*CO + lane] = acc_b;
    }
}

extern "C" void kernel_launch(void* const* d_in, const int* in_sizes, int n_in,
                              void* d_out, int out_size, void* d_ws, size_t ws_size,
                              hipStream_t stream) {
    const float* q_pts = (const float*)d_in[0];
    const float* s_pts = (const float*)d_in[1];
    const int*   inds  = (const int*)d_in[2];
    const float* x     = (const float*)d_in[3];
    const float* Wt    = (const float*)d_in[4];
    float* out = (float*)d_out;

    const int grid = (NQ + BQ - 1) / BQ;   // 5000
    kpconv_kernel<<<grid, 256, 0, stream>>>(q_pts, s_pts, inds, x, Wt, out);
}

// Round 2
// 183.754 us; speedup vs baseline: 2.7652x; 2.7652x over previous
//
#include <hip/hip_runtime.h>

typedef _Float16 half_t;
typedef _Float16 half2_t __attribute__((ext_vector_type(2)));
typedef _Float16 half8   __attribute__((ext_vector_type(8)));
typedef float    f32x4   __attribute__((ext_vector_type(4)));

#define NQ 40000
#define KP_S    0.057735026918962574f  // 0.1/sqrt(3)
#define INV_EXT 11.547005383792515f    // 1/(0.05*sqrt(3))

// WT[o][k], k = i*27 + l  (fp16), so stage-2 B-fragments are K-contiguous 16B loads.
__global__ void build_wt(const float* __restrict__ W, half_t* __restrict__ WT) {
    int t = blockIdx.x * 256 + threadIdx.x;
    if (t >= 64 * 1728) return;
    int o = t / 1728;
    int k = t - o * 1728;
    int i = k / 27;
    int l = k - i * 27;
    WT[t] = (half_t)W[(l * 64 + i) * 64 + o];
}

__device__ __forceinline__ int wkey(int l) { return ((l >> 1) ^ (l >> 3)) & 3; }

__global__ __launch_bounds__(256, 2) void kpconv(
    const float* __restrict__ q_pts, const float* __restrict__ s_pts,
    const int*   __restrict__ inds,  const float* __restrict__ x,
    const half_t* __restrict__ WT,   float* __restrict__ out)
{
    // LDS budget: 16384 + 20480 + 27648 + 512 = 65024 B (<= 64 KiB)
    __shared__ __align__(16) half_t w_lds[8 * 32 * 32];   // [q][l][h], h XOR-block-swizzled
    __shared__ __align__(16) half_t x_lds[4][64][40];     // per-wave [i][h], padded rows
    __shared__ __align__(16) char   g_mem[8 * 1728 * 2];  // G[q][k] fp16, row-XOR; aliases nbr
    __shared__ unsigned short idx_lds[8][32];

    float (*nbr)[32][3] = (float (*)[32][3])g_mem;  // only live phases A..B

    const int tid  = threadIdx.x;
    const int lane = tid & 63, wid = tid >> 6;
    const int base = blockIdx.x * 8;

    // ---- Phase A: indices + neighbor offsets ----
    {
        int q = tid >> 5, h = tid & 31;
        int n = base + q;
        int idx = inds[n * 32 + h];
        idx_lds[q][h] = (unsigned short)idx;
        nbr[q][h][0] = s_pts[idx * 3 + 0] - q_pts[n * 3 + 0];
        nbr[q][h][1] = s_pts[idx * 3 + 1] - q_pts[n * 3 + 1];
        nbr[q][h][2] = s_pts[idx * 3 + 2] - q_pts[n * 3 + 2];
    }
    __syncthreads();

    // ---- Phase B: influence weights -> w_lds[q][l][h] (A-operand layout) ----
    for (int t = tid; t < 4096; t += 256) {           // 8q * 32l * 16hp
        int q = t >> 9, l = (t >> 4) & 31, hp = t & 15;
        half2_t hv; hv[0] = (half_t)0.f; hv[1] = (half_t)0.f;
        if (l < 27) {
            float kx = (float)((l / 3) % 3 - 1) * KP_S;
            float ky = (float)(l / 9 - 1)       * KP_S;
            float kz = (float)(l % 3 - 1)       * KP_S;
            #pragma unroll
            for (int u = 0; u < 2; ++u) {
                int h = 2 * hp + u;
                float dx = nbr[q][h][0] - kx;
                float dy = nbr[q][h][1] - ky;
                float dz = nbr[q][h][2] - kz;
                float w = fmaxf(1.f - sqrtf(dx * dx + dy * dy + dz * dz) * INV_EXT, 0.f);
                hv[u] = (half_t)w;
            }
        }
        int blk = (hp >> 2) ^ wkey(l);
        int off = (q * 32 + l) * 32 + (blk << 3) + ((2 * hp) & 7);
        *(half2_t*)&w_lds[off] = hv;
    }
    __syncthreads();

    // ---- Phase C: per-wave, 2 queries: gather x (transposed) + stage-1 MFMA ----
    const int lr = lane & 15, g = lane >> 4;
    #pragma unroll
    for (int qq = 0; qq < 2; ++qq) {
        int q = wid * 2 + qq;
        float xv[32];
        #pragma unroll
        for (int h = 0; h < 32; ++h)
            xv[h] = x[(int)idx_lds[q][h] * 64 + lane];
        #pragma unroll
        for (int h = 0; h < 32; ++h)
            x_lds[wid][lane][h] = (half_t)xv[h];
        __asm__ volatile("s_waitcnt lgkmcnt(0)" ::: "memory");

        // A-frags: A[l][h] = w, rows l = lr (+16), K-run h = 8g..8g+7 (swizzled block)
        int l0 = lr, l1 = 16 + lr;
        half8 a0 = *(const half8*)&w_lds[(q * 32 + l0) * 32 + ((g ^ wkey(l0)) << 3)];
        half8 a1 = *(const half8*)&w_lds[(q * 32 + l1) * 32 + ((g ^ wkey(l1)) << 3)];

        f32x4 acc[2][4];
        #pragma unroll
        for (int nt = 0; nt < 4; ++nt) {
            // B-frag: B[h][i] = x, col i = 16nt+lr, K-run h = 8g..8g+7
            half8 b = *(const half8*)&x_lds[wid][16 * nt + lr][8 * g];
            f32x4 z = {0.f, 0.f, 0.f, 0.f};
            acc[0][nt] = __builtin_amdgcn_mfma_f32_16x16x32_f16(a0, b, z, 0, 0, 0);
            acc[1][nt] = __builtin_amdgcn_mfma_f32_16x16x32_f16(a1, b, z, 0, 0, 0);
        }

        // Dump D -> G[q][k = i*27 + l] (fp16, row-XOR by bit4)
        int qx = (q & 3) << 4;
        #pragma unroll
        for (int mt = 0; mt < 2; ++mt) {
            #pragma unroll
            for (int nt = 0; nt < 4; ++nt) {
                int i  = 16 * nt + lr;
                int lb = 16 * mt + 4 * g;
                #pragma unroll
                for (int r = 0; r < 4; ++r) {
                    int l = lb + r;
                    if (l < 27) {
                        int k = i * 27 + l;
                        *(half_t*)(g_mem + q * 3456 + ((2 * k) ^ qx)) = (half_t)acc[mt][nt][r];
                    }
                }
            }
        }
        __asm__ volatile("s_waitcnt lgkmcnt(0)" ::: "memory");
    }
    __syncthreads();

    // ---- Phase D: fx[8q,64o] = G[8,1728] @ Wflat[1728,64]; wave owns o-tile=wid ----
    {
        const half_t* wrow = WT + (16 * wid + lr) * 1728 + 8 * g;
        int q8 = lr & 7;                       // rows 8..15 alias 0..7 (duplicates, ignored)
        const char* gb = g_mem + q8 * 3456;
        int gx = (q8 & 3) << 4;
        f32x4 accA = {0, 0, 0, 0}, accB = {0, 0, 0, 0};
        #pragma unroll 3
        for (int s = 0; s < 54; s += 2) {
            half8 aA = *(const half8*)(gb + ((64 * s + 16 * g) ^ gx));
            half8 bA = *(const half8*)(wrow + 32 * s);
            accA = __builtin_amdgcn_mfma_f32_16x16x32_f16(aA, bA, accA, 0, 0, 0);
            half8 aB = *(const half8*)(gb + ((64 * (s + 1) + 16 * g) ^ gx));
            half8 bB = *(const half8*)(wrow + 32 * (s + 1));
            accB = __builtin_amdgcn_mfma_f32_16x16x32_f16(aB, bB, accB, 0, 0, 0);
        }
        f32x4 acc = accA + accB;
        if (g < 2) {                           // D rows 0..7 are the real queries
            int o = 16 * wid + lr;
            #pragma unroll
            for (int r = 0; r < 4; ++r) {
                int row = 4 * g + r;
                out[(base + row) * 64 + o] = acc[r];
            }
        }
    }
}

extern "C" void kernel_launch(void* const* d_in, const int* in_sizes, int n_in,
                              void* d_out, int out_size, void* d_ws, size_t ws_size,
                              hipStream_t stream) {
    const float* q_pts = (const float*)d_in[0];
    const float* s_pts = (const float*)d_in[1];
    const int*   inds  = (const int*)d_in[2];
    const float* x     = (const float*)d_in[3];
    const float* W     = (const float*)d_in[4];
    float* out = (float*)d_out;
    half_t* WT = (half_t*)d_ws;                // 64*1728*2 = 221184 B

    build_wt<<<432, 256, 0, stream>>>(W, WT);  // 432*256 = 110592 threads, exact
    kpconv<<<5000, 256, 0, stream>>>(q_pts, s_pts, inds, x, WT, out);
}

// Round 3
// 161.374 us; speedup vs baseline: 3.1487x; 1.1387x over previous
//
#include <hip/hip_runtime.h>

typedef _Float16 half_t;
typedef _Float16 half2_t __attribute__((ext_vector_type(2)));
typedef _Float16 half4_t __attribute__((ext_vector_type(4)));
typedef _Float16 half8   __attribute__((ext_vector_type(8)));
typedef float    f32x4   __attribute__((ext_vector_type(4)));
typedef unsigned short u16x8 __attribute__((ext_vector_type(8)));

#define KP_S    0.057735026918962574f  // 0.1/sqrt(3)
#define INV_EXT 11.547005383792515f    // 1/(0.05*sqrt(3))
#define GPITCH  3616                   // G bytes per query: 64*28*2=3584 data + 32 pad (bank spread)

// WT[o][k], k = i*28 + l (fp16); l==27 is a zero pad column mirroring G's pitch-28 pad.
__global__ void build_wt(const float* __restrict__ W, half_t* __restrict__ WT) {
    int t = blockIdx.x * 256 + threadIdx.x;       // 64*1792 = 114688 exact
    if (t >= 64 * 1792) return;
    int o = t / 1792, k = t - o * 1792;
    int i = k / 28,   l = k - i * 28;
    WT[t] = (l < 27) ? (half_t)W[(l * 64 + i) * 64 + o] : (half_t)0.f;
}

__device__ __forceinline__ int wkey(int l) { return ((l >> 1) ^ (l >> 3)) & 3; }

__global__ __launch_bounds__(256, 3) void kpconv(
    const float* __restrict__ q_pts, const float* __restrict__ s_pts,
    const int*   __restrict__ inds,  const float* __restrict__ x,
    const half_t* __restrict__ WT,   float* __restrict__ out)
{
    // LDS: 16384 + 28928 + 512 = 45824 B -> 3 blocks/CU
    __shared__ __align__(16) half_t w_lds[8 * 32 * 32];   // [q][l][h], h-block XOR swizzle
    __shared__ __align__(16) char   g_mem[8 * GPITCH];    // G[q][i*28+l] fp16
    __shared__ __align__(16) unsigned short idx_lds[8][32];

    float (*nbr)[32][3] = (float (*)[32][3])g_mem;        // alias, live phases A..B only

    const int tid  = threadIdx.x;
    const int lane = tid & 63, wid = tid >> 6;
    const int lr   = lane & 15, g = lane >> 4;
    const int base = blockIdx.x * 8;

    // ---- Phase A: indices + neighbor offsets ----
    {
        int q = tid >> 5, h = tid & 31;
        int n = base + q;
        int idx = inds[n * 32 + h];
        idx_lds[q][h] = (unsigned short)idx;
        nbr[q][h][0] = s_pts[idx * 3 + 0] - q_pts[n * 3 + 0];
        nbr[q][h][1] = s_pts[idx * 3 + 1] - q_pts[n * 3 + 1];
        nbr[q][h][2] = s_pts[idx * 3 + 2] - q_pts[n * 3 + 2];
    }
    __syncthreads();

    // ---- Phase B: influence weights -> w_lds[q][l][h] (A-operand layout) ----
    for (int t = tid; t < 4096; t += 256) {               // 8q * 32l * 16hp
        int q = t >> 9, l = (t >> 4) & 31, hp = t & 15;
        half2_t hv; hv[0] = (half_t)0.f; hv[1] = (half_t)0.f;
        if (l < 27) {
            float kx = (float)((l / 3) % 3 - 1) * KP_S;
            float ky = (float)(l / 9 - 1)       * KP_S;
            float kz = (float)(l % 3 - 1)       * KP_S;
            #pragma unroll
            for (int u = 0; u < 2; ++u) {
                int h = 2 * hp + u;
                float dx = nbr[q][h][0] - kx;
                float dy = nbr[q][h][1] - ky;
                float dz = nbr[q][h][2] - kz;
                float w = fmaxf(1.f - sqrtf(dx * dx + dy * dy + dz * dz) * INV_EXT, 0.f);
                hv[u] = (half_t)w;
            }
        }
        int blk = (hp >> 2) ^ wkey(l);
        int off = (q * 32 + l) * 32 + (blk << 3) + ((2 * hp) & 7);
        *(half2_t*)&w_lds[off] = hv;
    }
    __syncthreads();

    // ---- Phase C: per wave 2 queries; B-frags straight from global; G -> LDS ----
    #pragma unroll
    for (int qq = 0; qq < 2; ++qq) {
        int q = wid * 2 + qq;
        u16x8 id8 = *(const u16x8*)&idx_lds[q][8 * g];     // this lane's 8 h-rows
        const float* xp0 = x + (int)id8[0] * 64 + lr;
        const float* xp1 = x + (int)id8[1] * 64 + lr;
        const float* xp2 = x + (int)id8[2] * 64 + lr;
        const float* xp3 = x + (int)id8[3] * 64 + lr;
        const float* xp4 = x + (int)id8[4] * 64 + lr;
        const float* xp5 = x + (int)id8[5] * 64 + lr;
        const float* xp6 = x + (int)id8[6] * 64 + lr;
        const float* xp7 = x + (int)id8[7] * 64 + lr;

        float xv[4][8];
        #pragma unroll
        for (int nt = 0; nt < 4; ++nt) {
            xv[nt][0] = xp0[16 * nt]; xv[nt][1] = xp1[16 * nt];
            xv[nt][2] = xp2[16 * nt]; xv[nt][3] = xp3[16 * nt];
            xv[nt][4] = xp4[16 * nt]; xv[nt][5] = xp5[16 * nt];
            xv[nt][6] = xp6[16 * nt]; xv[nt][7] = xp7[16 * nt];
        }

        int l0 = lr, l1 = 16 + lr;
        half8 a0 = *(const half8*)&w_lds[(q * 32 + l0) * 32 + ((g ^ wkey(l0)) << 3)];
        half8 a1 = *(const half8*)&w_lds[(q * 32 + l1) * 32 + ((g ^ wkey(l1)) << 3)];

        f32x4 acc[2][4];
        #pragma unroll
        for (int nt = 0; nt < 4; ++nt) {
            half8 b;
            #pragma unroll
            for (int j = 0; j < 8; ++j) b[j] = (half_t)xv[nt][j];
            f32x4 z = {0.f, 0.f, 0.f, 0.f};
            acc[0][nt] = __builtin_amdgcn_mfma_f32_16x16x32_f16(a0, b, z, 0, 0, 0);
            acc[1][nt] = __builtin_amdgcn_mfma_f32_16x16x32_f16(a1, b, z, 0, 0, 0);
        }

        // G dump: rows l..l+3 contiguous at k=i*28+l -> packed 8B writes
        char* gq = g_mem + q * GPITCH;
        #pragma unroll
        for (int mt = 0; mt < 2; ++mt) {
            int lb = 16 * mt + 4 * g;
            #pragma unroll
            for (int nt = 0; nt < 4; ++nt) {
                half4_t hv;
                hv[0] = (half_t)acc[mt][nt][0]; hv[1] = (half_t)acc[mt][nt][1];
                hv[2] = (half_t)acc[mt][nt][2]; hv[3] = (half_t)acc[mt][nt][3];
                int i = 16 * nt + lr;
                if (lb < 28)                                  // only mt==1,g==3 masked off
                    *(half4_t*)(gq + 2 * (i * 28 + lb)) = hv;
            }
        }
    }
    __syncthreads();

    // ---- Phase D: fx[16,64] = G[16,1792] @ WT^T; wave owns o-tile = wid ----
    {
        const half_t* wrow = WT + (16 * wid + lr) * 1792 + 8 * g;
        int q8 = lr & 7;                                      // rows 8..15 duplicate 0..7
        const char* gb = g_mem + q8 * GPITCH;
        f32x4 accA = {0.f, 0.f, 0.f, 0.f}, accB = {0.f, 0.f, 0.f, 0.f};
        #pragma unroll 4
        for (int s = 0; s < 56; s += 2) {
            half8 aA = *(const half8*)(gb + 64 * s + 16 * g);
            half8 bA = *(const half8*)(wrow + 32 * s);
            accA = __builtin_amdgcn_mfma_f32_16x16x32_f16(aA, bA, accA, 0, 0, 0);
            half8 aB = *(const half8*)(gb + 64 * (s + 1) + 16 * g);
            half8 bB = *(const half8*)(wrow + 32 * (s + 1));
            accB = __builtin_amdgcn_mfma_f32_16x16x32_f16(aB, bB, accB, 0, 0, 0);
        }
        f32x4 acc = accA + accB;
        if (g < 2) {                                          // D rows 0..7 = real queries
            int o = 16 * wid + lr;
            #pragma unroll
            for (int r = 0; r < 4; ++r)
                out[(base + 4 * g + r) * 64 + o] = acc[r];
        }
    }
}

extern "C" void kernel_launch(void* const* d_in, const int* in_sizes, int n_in,
                              void* d_out, int out_size, void* d_ws, size_t ws_size,
                              hipStream_t stream) {
    const float* q_pts = (const float*)d_in[0];
    const float* s_pts = (const float*)d_in[1];
    const int*   inds  = (const int*)d_in[2];
    const float* x     = (const float*)d_in[3];
    const float* W     = (const float*)d_in[4];
    float* out = (float*)d_out;
    half_t* WT = (half_t*)d_ws;                 // 64*1792*2 = 229376 B

    build_wt<<<448, 256, 0, stream>>>(W, WT);   // 448*256 = 114688 exact
    kpconv<<<5000, 256, 0, stream>>>(q_pts, s_pts, inds, x, WT, out);
}

// Round 4
// 108.576 us; speedup vs baseline: 4.6798x; 1.4863x over previous
//
#include <hip/hip_runtime.h>

typedef _Float16 half_t;
typedef _Float16 half4_t __attribute__((ext_vector_type(4)));
typedef _Float16 half8   __attribute__((ext_vector_type(8)));
typedef float    f32x4   __attribute__((ext_vector_type(4)));
typedef unsigned short u16x8 __attribute__((ext_vector_type(8)));

#define KP_S    0.057735026918962574f  // 0.1/sqrt(3)
#define INV_EXT 11.547005383792515f    // 1/(0.05*sqrt(3))
#define GPITCH  3616                   // G bytes/query: 64*28*2 data + 32 pad (mod128=32 -> uniform banks)
#define BQ      16

// WT[o][k], k = i*28 + l (fp16); l==27 zero pad column mirrors G's pitch-28 pad.
__global__ void build_wt(const float* __restrict__ W, half_t* __restrict__ WT) {
    int t = blockIdx.x * 256 + threadIdx.x;       // 64*1792 = 114688 exact
    if (t >= 64 * 1792) return;
    int o = t / 1792, k = t - o * 1792;
    int i = k / 28,   l = k - i * 28;
    WT[t] = (l < 27) ? (half_t)W[(l * 64 + i) * 64 + o] : (half_t)0.f;
}

__global__ __launch_bounds__(512, 4) void kpconv(
    const float* __restrict__ q_pts, const float* __restrict__ s_pts,
    const int*   __restrict__ inds,  const float* __restrict__ x,
    const half_t* __restrict__ WT,   float* __restrict__ out)
{
    // LDS: 57856 + 1024 + 4096 = 62976 B -> 2 blocks/CU (16 waves/CU)
    __shared__ __align__(16) char   g_mem[BQ * GPITCH];     // G[q][i*28+l] fp16; bytes 0..511 alias nbr[q]
    __shared__ __align__(16) unsigned short idx_lds[BQ][32];
    __shared__ __align__(16) f32x4  red[4][64];             // phase-D cross-wave K-reduction

    const int tid  = threadIdx.x;
    const int lane = tid & 63, wid = tid >> 6;
    const int lr   = lane & 15, g = lane >> 4;
    const int base = blockIdx.x * BQ;

    // ---- Phase A: indices + neighbor offsets (nbr[q][h] in G[q]'s first 512 B) ----
    {
        int q = tid >> 5, h = tid & 31;
        int n = base + q;
        int idx = inds[n * 32 + h];
        idx_lds[q][h] = (unsigned short)idx;
        f32x4 v;
        v.x = s_pts[idx * 3 + 0] - q_pts[n * 3 + 0];
        v.y = s_pts[idx * 3 + 1] - q_pts[n * 3 + 1];
        v.z = s_pts[idx * 3 + 2] - q_pts[n * 3 + 2];
        v.w = 0.f;
        *(f32x4*)(g_mem + q * GPITCH + h * 16) = v;
    }
    __syncthreads();

    // ---- Phase C: per wave 2 queries; per-lane w; B-frags from global; G -> LDS ----
    // This lane's kernel-point coords: rows l0 = lr, l1 = lr + 16 (l1 >= 27 -> w = 0)
    const float kx0 = (float)((lr / 3) % 3 - 1) * KP_S;
    const float ky0 = (float)( lr / 9      - 1) * KP_S;
    const float kz0 = (float)( lr % 3      - 1) * KP_S;
    const int   l1  = lr + 16;
    const bool  hv1 = (l1 < 27);
    const float kx1 = (float)((l1 / 3) % 3 - 1) * KP_S;
    const float ky1 = (float)( l1 / 9      - 1) * KP_S;
    const float kz1 = (float)( l1 % 3      - 1) * KP_S;

    for (int qq = 0; qq < 2; ++qq) {
        const int q = wid * 2 + qq;
        char* gq = g_mem + q * GPITCH;

        // x gather: this lane's 8 h-rows (h = 8g..8g+7), columns i = 16nt + lr
        u16x8 id8 = *(const u16x8*)&idx_lds[q][8 * g];
        float xv[32];
        #pragma unroll
        for (int j = 0; j < 8; ++j) {
            const float* xp = x + (int)id8[j] * 64 + lr;
            #pragma unroll
            for (int nt = 0; nt < 4; ++nt) xv[nt * 8 + j] = xp[16 * nt];
        }

        // per-lane influence weights from broadcast nbr reads (A-frag in registers)
        half8 a0, a1;
        #pragma unroll
        for (int j = 0; j < 8; ++j) {
            f32x4 nb = *(const f32x4*)(gq + (8 * g + j) * 16);
            float dx = nb.x - kx0, dy = nb.y - ky0, dz = nb.z - kz0;
            float s0 = dx * dx + dy * dy + dz * dz;
            a0[j] = (half_t)fmaxf(1.f - sqrtf(s0) * INV_EXT, 0.f);
            float ex = nb.x - kx1, ey = nb.y - ky1, ez = nb.z - kz1;
            float s1 = ex * ex + ey * ey + ez * ez;
            float w1 = fmaxf(1.f - sqrtf(s1) * INV_EXT, 0.f);
            a1[j] = (half_t)(hv1 ? w1 : 0.f);
        }

        // stage-1 MFMAs per nt, dump G immediately (keeps register pressure low)
        #pragma unroll
        for (int nt = 0; nt < 4; ++nt) {
            half8 b;
            #pragma unroll
            for (int j = 0; j < 8; ++j) b[j] = (half_t)xv[nt * 8 + j];
            f32x4 z = {0.f, 0.f, 0.f, 0.f};
            f32x4 c0 = __builtin_amdgcn_mfma_f32_16x16x32_f16(a0, b, z, 0, 0, 0);
            f32x4 c1 = __builtin_amdgcn_mfma_f32_16x16x32_f16(a1, b, z, 0, 0, 0);
            int i = 16 * nt + lr;
            half4_t h0;
            h0[0] = (half_t)c0[0]; h0[1] = (half_t)c0[1];
            h0[2] = (half_t)c0[2]; h0[3] = (half_t)c0[3];
            *(half4_t*)(gq + 2 * (i * 28 + 4 * g)) = h0;           // l = 4g..4g+3
            int lb1 = 16 + 4 * g;
            if (lb1 < 28) {                                        // g==3 -> l=28..31 padding, skip
                half4_t h1;
                h1[0] = (half_t)c1[0]; h1[1] = (half_t)c1[1];
                h1[2] = (half_t)c1[2]; h1[3] = (half_t)c1[3];
                *(half4_t*)(gq + 2 * (i * 28 + lb1)) = h1;         // l = 16+4g..19+4g
            }
        }
    }
    __syncthreads();

    // ---- Phase D: fx[16,64] = G[16,1792] @ WT^T; wave = (o-tile, K-half) ----
    {
        const int ot = wid & 3, kh = wid >> 2;
        const half_t* wrow = WT + (16 * ot + lr) * 1792 + kh * 896 + 8 * g;
        const char*   gb   = g_mem + lr * GPITCH + kh * 1792;
        f32x4 accA = {0.f, 0.f, 0.f, 0.f}, accB = {0.f, 0.f, 0.f, 0.f};
        #pragma unroll 7
        for (int s = 0; s < 28; s += 2) {
            half8 aA = *(const half8*)(gb + 64 * s + 16 * g);
            half8 bA = *(const half8*)(wrow + 32 * s);
            accA = __builtin_amdgcn_mfma_f32_16x16x32_f16(aA, bA, accA, 0, 0, 0);
            half8 aB = *(const half8*)(gb + 64 * (s + 1) + 16 * g);
            half8 bB = *(const half8*)(wrow + 32 * (s + 1));
            accB = __builtin_amdgcn_mfma_f32_16x16x32_f16(aB, bB, accB, 0, 0, 0);
        }
        f32x4 acc = accA + accB;
        if (kh == 1) *(f32x4*)&red[ot][lane] = acc;
        __syncthreads();
        if (kh == 0) {
            f32x4 p = red[ot][lane];
            acc.x += p.x; acc.y += p.y; acc.z += p.z; acc.w += p.w;
            int o = 16 * ot + lr;
            #pragma unroll
            for (int r = 0; r < 4; ++r)
                out[(base + 4 * g + r) * 64 + o] = acc[r];
        }
    }
}

extern "C" void kernel_launch(void* const* d_in, const int* in_sizes, int n_in,
                              void* d_out, int out_size, void* d_ws, size_t ws_size,
                              hipStream_t stream) {
    const float* q_pts = (const float*)d_in[0];
    const float* s_pts = (const float*)d_in[1];
    const int*   inds  = (const int*)d_in[2];
    const float* x     = (const float*)d_in[3];
    const float* W     = (const float*)d_in[4];
    float* out = (float*)d_out;
    half_t* WT = (half_t*)d_ws;                 // 64*1792*2 = 229376 B

    build_wt<<<448, 256, 0, stream>>>(W, WT);   // 448*256 = 114688 exact
    kpconv<<<2500, 512, 0, stream>>>(q_pts, s_pts, inds, x, WT, out);
}